// Round 1
// baseline (889.054 us; speedup 1.0000x reference)
//
#include <hip/hip_runtime.h>
#include <math.h>

#define D 128
#define A 5
#define TM 64
#define CSTR 68   // padded LDS stride for 64-wide combined tile (68*4B = 272B, 16B-aligned rows)

// ---------------- Kernel 1: node prompt (softmax attention over anchors) ----------------
__global__ __launch_bounds__(256) void node_prompt_kernel(
    const float* __restrict__ x,
    const float* __restrict__ attn_w, const float* __restrict__ attn_b,
    const float* __restrict__ anchor_node,
    float* __restrict__ node_px, int N)
{
    int t = threadIdx.x;
    int j = (t & 63) * 2;
    // Per-lane weights are edge-invariant: load once into registers (no LDS needed).
    float At0[A], At1[A], AN0[A], AN1[A], Ab[A];
    #pragma unroll
    for (int a = 0; a < A; a++) {
        At0[a] = attn_w[(size_t)j * A + a];
        At1[a] = attn_w[(size_t)(j + 1) * A + a];
        AN0[a] = anchor_node[a * D + j];
        AN1[a] = anchor_node[a * D + j + 1];
        Ab[a]  = attn_b[a];
    }
    int wid = blockIdx.x * 4 + (t >> 6);
    int nw  = gridDim.x * 4;
    for (int n = wid; n < N; n += nw) {
        float2 xv = *(const float2*)&x[(size_t)n * D + j];
        float l[A];
        #pragma unroll
        for (int a = 0; a < A; a++) {
            float p = xv.x * At0[a] + xv.y * At1[a];
            #pragma unroll
            for (int off = 32; off; off >>= 1) p += __shfl_xor(p, off);
            l[a] = p + Ab[a];
        }
        float m = l[0];
        #pragma unroll
        for (int a = 1; a < A; a++) m = fmaxf(m, l[a]);
        float s = 0.f;
        #pragma unroll
        for (int a = 0; a < A; a++) { l[a] = __expf(l[a] - m); s += l[a]; }
        float inv = 1.f / s;
        float2 o = xv;
        #pragma unroll
        for (int a = 0; a < A; a++) {
            float w = l[a] * inv;
            o.x += w * AN0[a];
            o.y += w * AN1[a];
        }
        *(float2*)&node_px[(size_t)n * D + j] = o;
    }
}

// ---------------- Kernel 2: edge prompt + rank-A coefficient scatter ----------------
// KEY CHANGE: edge_prompt[e] = b[e] @ anchor_edge is rank-A (A=5).
// agg[n] = (sum of b over incident edges) @ anchor_edge, so we scatter only the
// 5 softmax coefficients per endpoint (10 atomics/edge) instead of 128 floats
// per endpoint (256 atomics/edge). 25.6x fewer atomics; agg reconstructed later.
__global__ __launch_bounds__(256) void edge_kernel(
    const float* __restrict__ x, const int* __restrict__ ei,
    const float* __restrict__ w_w, const float* __restrict__ w_b,
    const float* __restrict__ anchor_edge,
    float* __restrict__ edge_prompt, float* __restrict__ bagg, int E, int N)
{
    int t = threadIdx.x;
    int j = (t & 63) * 2;
    // Per-lane slices of the weights, loaded once (w_w is [2D][A] row-major).
    float W0[A], W1[A], W2[A], W3[A], AE0[A], AE1[A], Wb[A];
    #pragma unroll
    for (int a = 0; a < A; a++) {
        W0[a]  = w_w[(size_t)j * A + a];
        W1[a]  = w_w[(size_t)(j + 1) * A + a];
        W2[a]  = w_w[(size_t)(D + j) * A + a];
        W3[a]  = w_w[(size_t)(D + j + 1) * A + a];
        AE0[a] = anchor_edge[a * D + j];
        AE1[a] = anchor_edge[a * D + j + 1];
        Wb[a]  = w_b[a];
    }
    int sub = t & 31;               // for coefficient scatter lanes
    int half = (t & 63) >> 5;       // 0: scatter to src, 1: scatter to dst

    int wid = blockIdx.x * 4 + (t >> 6);
    int nw  = gridDim.x * 4;
    for (int e = wid; e < E; e += nw) {
        int s = ei[e];
        int d = ei[(size_t)E + e];
        float2 xs = *(const float2*)&x[(size_t)s * D + j];
        float2 xd = *(const float2*)&x[(size_t)d * D + j];
        float l[A];
        #pragma unroll
        for (int a = 0; a < A; a++) {
            float p = xs.x * W0[a] + xs.y * W1[a]
                    + xd.x * W2[a] + xd.y * W3[a];
            #pragma unroll
            for (int off = 32; off; off >>= 1) p += __shfl_xor(p, off);
            p += Wb[a];
            l[a] = (p > 0.f) ? p : 0.01f * p;   // leaky_relu (slope 0.01)
        }
        float m = l[0];
        #pragma unroll
        for (int a = 1; a < A; a++) m = fmaxf(m, l[a]);
        float sum = 0.f;
        #pragma unroll
        for (int a = 0; a < A; a++) { l[a] = __expf(l[a] - m); sum += l[a]; }
        float inv = 1.f / sum;
        float2 ep = make_float2(0.f, 0.f);
        #pragma unroll
        for (int a = 0; a < A; a++) {
            float b = l[a] * inv;
            ep.x += b * AE0[a];
            ep.y += b * AE1[a];
        }
        *(float2*)&edge_prompt[(size_t)e * D + j] = ep;

        // scatter the A softmax coefficients: lanes 0..A-1 -> src, 32..32+A-1 -> dst
        if (sub < A) {
            float bv = 0.f;
            #pragma unroll
            for (int a = 0; a < A; a++) if (sub == a) bv = l[a] * inv;
            int node = half ? d : s;
            atomicAdd(&bagg[(size_t)node * A + sub], bv);
        }
    }
}

// ---------------- Kernel 2b: agg = bagg @ anchor_edge  (N x A x D, tiny) ----------------
__global__ __launch_bounds__(256) void agg_kernel(
    const float* __restrict__ bagg, const float* __restrict__ anchor_edge,
    float* __restrict__ agg, int N)
{
    __shared__ float AE[A * D];
    int t = threadIdx.x;
    for (int f = t; f < A * D; f += 256) AE[f] = anchor_edge[f];
    __syncthreads();
    int total = N * (D / 4);   // float4 chunks
    for (int i = blockIdx.x * 256 + t; i < total; i += gridDim.x * 256) {
        int n = i >> 5;
        int c = (i & 31) * 4;
        const float* br = &bagg[(size_t)n * A];
        float b0 = br[0], b1 = br[1], b2 = br[2], b3 = br[3], b4 = br[4];
        float4 e0 = *(float4*)&AE[0 * D + c];
        float4 e1 = *(float4*)&AE[1 * D + c];
        float4 e2 = *(float4*)&AE[2 * D + c];
        float4 e3 = *(float4*)&AE[3 * D + c];
        float4 e4 = *(float4*)&AE[4 * D + c];
        float4 r;
        r.x = b0 * e0.x + b1 * e1.x + b2 * e2.x + b3 * e3.x + b4 * e4.x;
        r.y = b0 * e0.y + b1 * e1.y + b2 * e2.y + b3 * e3.y + b4 * e4.y;
        r.z = b0 * e0.z + b1 * e1.z + b2 * e2.z + b3 * e3.z + b4 * e4.z;
        r.w = b0 * e0.w + b1 * e1.w + b2 * e2.w + b3 * e3.w + b4 * e4.w;
        *(float4*)&agg[(size_t)n * D + c] = r;
    }
}

// ---------------- helper: 4x4 outer-product FMA ----------------
__device__ __forceinline__ void fma4(float4& acc, const float4 cv,
                                     const float4 w0, const float4 w1,
                                     const float4 w2, const float4 w3)
{
    acc.x += cv.x * w0.x + cv.y * w1.x + cv.z * w2.x + cv.w * w3.x;
    acc.y += cv.x * w0.y + cv.y * w1.y + cv.z * w2.y + cv.w * w3.y;
    acc.z += cv.x * w0.z + cv.y * w1.z + cv.z * w2.z + cv.w * w3.z;
    acc.w += cv.x * w0.w + cv.y * w1.w + cv.z * w2.w + cv.w * w3.w;
}

// ---------------- Kernel 3a: h = relu([node_px, agg] @ cd1_w + cd1_b) ----------------
__global__ __launch_bounds__(256) void cd1_kernel(
    const float* __restrict__ node_px, const float* __restrict__ agg,
    const float* __restrict__ cd1_w, const float* __restrict__ cd1_b,
    float* __restrict__ h, int N)
{
    __shared__ float Wt[64 * D];       // 32 KB
    __shared__ float Cn[TM * CSTR];    // 17.4 KB
    int t = threadIdx.x;
    int n0 = blockIdx.x * TM;
    int cg = t & 31, ng = t >> 5;
    int c0 = cg * 4;
    float4 acc[8];
    #pragma unroll
    for (int jj = 0; jj < 8; jj++) acc[jj] = make_float4(0.f, 0.f, 0.f, 0.f);

    for (int kt = 0; kt < 4; kt++) {
        int k0 = kt * 64;
        __syncthreads();
        const float4* Wg = (const float4*)(cd1_w + (size_t)k0 * D);
        float4* Wl = (float4*)Wt;
        #pragma unroll
        for (int i = 0; i < 8; i++) Wl[i * 256 + t] = Wg[i * 256 + t];
        const float* src = (k0 < 128) ? node_px : agg;
        int koff = k0 & 127;
        #pragma unroll
        for (int i = 0; i < 4; i++) {
            int f = i * 256 + t;
            int n = f >> 4, k4 = f & 15;
            int nn = n0 + n; if (nn >= N) nn = N - 1;
            float4 v = *(const float4*)&src[(size_t)nn * D + koff + k4 * 4];
            *(float4*)&Cn[n * CSTR + k4 * 4] = v;
        }
        __syncthreads();
        #pragma unroll 4
        for (int k4 = 0; k4 < 16; k4++) {
            float4 w0 = *(float4*)&Wt[(k4 * 4 + 0) * D + c0];
            float4 w1 = *(float4*)&Wt[(k4 * 4 + 1) * D + c0];
            float4 w2 = *(float4*)&Wt[(k4 * 4 + 2) * D + c0];
            float4 w3 = *(float4*)&Wt[(k4 * 4 + 3) * D + c0];
            #pragma unroll
            for (int jj = 0; jj < 8; jj++) {
                float4 cv = *(float4*)&Cn[(ng * 8 + jj) * CSTR + k4 * 4];
                fma4(acc[jj], cv, w0, w1, w2, w3);
            }
        }
    }
    float4 b = *(const float4*)&cd1_b[c0];
    #pragma unroll
    for (int jj = 0; jj < 8; jj++) {
        int n = n0 + ng * 8 + jj;
        if (n < N) {
            float4 r;
            r.x = fmaxf(acc[jj].x + b.x, 0.f);
            r.y = fmaxf(acc[jj].y + b.y, 0.f);
            r.z = fmaxf(acc[jj].z + b.z, 0.f);
            r.w = fmaxf(acc[jj].w + b.w, 0.f);
            *(float4*)&h[(size_t)n * D + c0] = r;
        }
    }
}

// ---------------- Kernel 3b: cs = sigmoid(h @ cd2_w + cd2_b), in-place over h ----------------
__global__ __launch_bounds__(256) void cd2_kernel(
    const float* h_in, const float* __restrict__ cd2_w,
    const float* __restrict__ cd2_b, float* cs_out, int N)
{
    __shared__ float Wt[64 * D];
    __shared__ float Cn[TM * CSTR];
    int t = threadIdx.x;
    int n0 = blockIdx.x * TM;
    int cg = t & 31, ng = t >> 5;
    int c0 = cg * 4;
    float4 acc[8];
    #pragma unroll
    for (int jj = 0; jj < 8; jj++) acc[jj] = make_float4(0.f, 0.f, 0.f, 0.f);

    for (int kt = 0; kt < 2; kt++) {
        int k0 = kt * 64;
        __syncthreads();
        const float4* Wg = (const float4*)(cd2_w + (size_t)k0 * D);
        float4* Wl = (float4*)Wt;
        #pragma unroll
        for (int i = 0; i < 8; i++) Wl[i * 256 + t] = Wg[i * 256 + t];
        #pragma unroll
        for (int i = 0; i < 4; i++) {
            int f = i * 256 + t;
            int n = f >> 4, k4 = f & 15;
            int nn = n0 + n; if (nn >= N) nn = N - 1;
            float4 v = *(const float4*)&h_in[(size_t)nn * D + k0 + k4 * 4];
            *(float4*)&Cn[n * CSTR + k4 * 4] = v;
        }
        __syncthreads();
        #pragma unroll 4
        for (int k4 = 0; k4 < 16; k4++) {
            float4 w0 = *(float4*)&Wt[(k4 * 4 + 0) * D + c0];
            float4 w1 = *(float4*)&Wt[(k4 * 4 + 1) * D + c0];
            float4 w2 = *(float4*)&Wt[(k4 * 4 + 2) * D + c0];
            float4 w3 = *(float4*)&Wt[(k4 * 4 + 3) * D + c0];
            #pragma unroll
            for (int jj = 0; jj < 8; jj++) {
                float4 cv = *(float4*)&Cn[(ng * 8 + jj) * CSTR + k4 * 4];
                fma4(acc[jj], cv, w0, w1, w2, w3);
            }
        }
    }
    float4 b = *(const float4*)&cd2_b[c0];
    #pragma unroll
    for (int jj = 0; jj < 8; jj++) {
        int n = n0 + ng * 8 + jj;
        if (n < N) {
            float4 r;
            r.x = 1.f / (1.f + __expf(-(acc[jj].x + b.x)));
            r.y = 1.f / (1.f + __expf(-(acc[jj].y + b.y)));
            r.z = 1.f / (1.f + __expf(-(acc[jj].z + b.z)));
            r.w = 1.f / (1.f + __expf(-(acc[jj].w + b.w)));
            *(float4*)&cs_out[(size_t)n * D + c0] = r;
        }
    }
}

// ---------------- Kernel 3c: final = node_px + cs * ((node_px+agg) @ int_w + int_b) ----------------
// final_x written over node_px (same buffer): block-local read-before-write, safe.
__global__ __launch_bounds__(256) void final_kernel(
    const float* node_px, const float* __restrict__ agg,
    const float* __restrict__ cs, const float* __restrict__ int_w,
    const float* __restrict__ int_b, float* final_x, int N)
{
    __shared__ float Wt[64 * D];
    __shared__ float Cn[TM * CSTR];
    int t = threadIdx.x;
    int n0 = blockIdx.x * TM;
    int cg = t & 31, ng = t >> 5;
    int c0 = cg * 4;
    float4 acc[8];
    #pragma unroll
    for (int jj = 0; jj < 8; jj++) acc[jj] = make_float4(0.f, 0.f, 0.f, 0.f);

    for (int kt = 0; kt < 2; kt++) {
        int k0 = kt * 64;
        __syncthreads();
        const float4* Wg = (const float4*)(int_w + (size_t)k0 * D);
        float4* Wl = (float4*)Wt;
        #pragma unroll
        for (int i = 0; i < 8; i++) Wl[i * 256 + t] = Wg[i * 256 + t];
        #pragma unroll
        for (int i = 0; i < 4; i++) {
            int f = i * 256 + t;
            int n = f >> 4, k4 = f & 15;
            int nn = n0 + n; if (nn >= N) nn = N - 1;
            float4 a4 = *(const float4*)&node_px[(size_t)nn * D + k0 + k4 * 4];
            float4 b4 = *(const float4*)&agg[(size_t)nn * D + k0 + k4 * 4];
            float4 v = make_float4(a4.x + b4.x, a4.y + b4.y, a4.z + b4.z, a4.w + b4.w);
            *(float4*)&Cn[n * CSTR + k4 * 4] = v;
        }
        __syncthreads();
        #pragma unroll 4
        for (int k4 = 0; k4 < 16; k4++) {
            float4 w0 = *(float4*)&Wt[(k4 * 4 + 0) * D + c0];
            float4 w1 = *(float4*)&Wt[(k4 * 4 + 1) * D + c0];
            float4 w2 = *(float4*)&Wt[(k4 * 4 + 2) * D + c0];
            float4 w3 = *(float4*)&Wt[(k4 * 4 + 3) * D + c0];
            #pragma unroll
            for (int jj = 0; jj < 8; jj++) {
                float4 cv = *(float4*)&Cn[(ng * 8 + jj) * CSTR + k4 * 4];
                fma4(acc[jj], cv, w0, w1, w2, w3);
            }
        }
    }
    float4 b = *(const float4*)&int_b[c0];
    #pragma unroll
    for (int jj = 0; jj < 8; jj++) {
        int n = n0 + ng * 8 + jj;
        if (n < N) {
            float4 iv = make_float4(acc[jj].x + b.x, acc[jj].y + b.y,
                                    acc[jj].z + b.z, acc[jj].w + b.w);
            float4 c4 = *(const float4*)&cs[(size_t)n * D + c0];
            float4 np = *(const float4*)&node_px[(size_t)n * D + c0];
            float4 r;
            r.x = np.x + c4.x * iv.x;
            r.y = np.y + c4.y * iv.y;
            r.z = np.z + c4.z * iv.z;
            r.w = np.w + c4.w * iv.w;
            *(float4*)&final_x[(size_t)n * D + c0] = r;
        }
    }
}

extern "C" void kernel_launch(void* const* d_in, const int* in_sizes, int n_in,
                              void* d_out, int out_size, void* d_ws, size_t ws_size,
                              hipStream_t stream)
{
    const float* x           = (const float*)d_in[0];
    const float* anchor_node = (const float*)d_in[1];
    const float* attn_w      = (const float*)d_in[2];
    const float* attn_b      = (const float*)d_in[3];
    const float* anchor_edge = (const float*)d_in[4];
    const float* w_w         = (const float*)d_in[5];
    const float* w_b         = (const float*)d_in[6];
    const float* cd1_w       = (const float*)d_in[7];
    const float* cd1_b       = (const float*)d_in[8];
    const float* cd2_w       = (const float*)d_in[9];
    const float* cd2_b       = (const float*)d_in[10];
    const float* int_w       = (const float*)d_in[11];
    const float* int_b       = (const float*)d_in[12];
    const int*   ei          = (const int*)d_in[13];

    int N = in_sizes[0] / D;
    int E = in_sizes[13] / 2;

    float* out         = (float*)d_out;
    float* node_px     = out;                       // reuse final_x slot for node_px
    float* edge_prompt = out + (size_t)N * D;
    float* agg         = (float*)d_ws;              // N*D floats
    float* h           = agg + (size_t)N * D;       // N*D floats (h, then cs in-place)
    float* bagg        = h;                         // N*A floats; dead before cd1 writes h

    // only the tiny coefficient accumulator needs zeroing now (1 MB vs 25.6 MB)
    hipMemsetAsync(bagg, 0, (size_t)N * A * sizeof(float), stream);

    node_prompt_kernel<<<512, 256, 0, stream>>>(x, attn_w, attn_b, anchor_node, node_px, N);
    edge_kernel<<<2048, 256, 0, stream>>>(x, ei, w_w, w_b, anchor_edge, edge_prompt, bagg, E, N);
    agg_kernel<<<2048, 256, 0, stream>>>(bagg, anchor_edge, agg, N);

    int nb = (N + TM - 1) / TM;
    cd1_kernel<<<nb, 256, 0, stream>>>(node_px, agg, cd1_w, cd1_b, h, N);
    cd2_kernel<<<nb, 256, 0, stream>>>(h, cd2_w, cd2_b, h, N);
    final_kernel<<<nb, 256, 0, stream>>>(node_px, agg, h, int_w, int_b, node_px, N);
}